// Round 14
// baseline (555.830 us; speedup 1.0000x reference)
//
#include <hip/hip_runtime.h>
#include <hip/hip_bf16.h>
#include <hip/hip_fp16.h>

#define NN 50000
#define NE 800000
#define MP 50048            // NN padded to multiple of 128
#define SCAN_NB 196         // ceil(NN/256)
#define GE_NB 3125          // ceil(NE/256)
#define CVT_XB 6256         // MP*128/4/256 blocks for x conversion
#define CVT_WB 448          // 7*16384/256 blocks for w conversion

typedef __bf16 bf16x8 __attribute__((ext_vector_type(8)));
typedef unsigned short u16x8 __attribute__((ext_vector_type(8)));
typedef float f32x4 __attribute__((ext_vector_type(4)));

static __device__ __forceinline__ float b2f(unsigned short u) {
  union { unsigned int i; float f; } v; v.i = ((unsigned int)u) << 16; return v.f;
}
static __device__ __forceinline__ unsigned short f2b(float f) {
  __hip_bfloat16 h = __float2bfloat16(f);
  union { __hip_bfloat16 h; unsigned short u; } v; v.h = h; return v.u;
}
static __device__ __forceinline__ float h2f_bits(unsigned short u) {
  __half h; union { __half h; unsigned short u; } v; v.u = u; h = v.h;
  return __half2float(h);
}
static __device__ __forceinline__ unsigned short f2h_bits(float f) {
  union { __half h; unsigned short u; } v; v.h = __float2half_rn(f); return v.u;
}

static __device__ __forceinline__ int get_src(const int* ei, int f, int i) {
  return f ? ei[2 * i] : ei[i];
}
static __device__ __forceinline__ int get_dst(const int* ei, int f, int i) {
  return f ? ei[2 * (NE + i)] : ei[NE + i];
}

// exact bf16 hi/lo split of 8 fp16 values (fp16 has 11-bit mantissa: hi =
// trunc-to-bf16 keeps top 8, residual lo has <=3 significant bits -> both
// bf16-exact; hi+lo == value exactly)
static __device__ __forceinline__ void split8(const __half* h8, bf16x8& ah, bf16x8& al) {
  u16x8 hu, lu;
#pragma unroll
  for (int i = 0; i < 8; ++i) {
    float f = __half2float(h8[i]);
    unsigned uf = __float_as_uint(f);
    unsigned hb = uf & 0xffff0000u;
    hu[i] = (unsigned short)(hb >> 16);
    float lo = f - __uint_as_float(hb);
    lu[i] = (unsigned short)(__float_as_uint(lo) >> 16);
  }
  ah = *(bf16x8*)&hu;
  al = *(bf16x8*)&lu;
}

// ---------------- fused: flag detect + dc init + cvt_x + cvt_w ----------------
__global__ __launch_bounds__(256) void prep_fused(const int* __restrict__ ei,
    int* flag, unsigned long long* dc,
    const float* __restrict__ x, __half* __restrict__ Hf,
    const float* __restrict__ W1, const float* __restrict__ Wm,
    unsigned short* __restrict__ Wth, unsigned short* __restrict__ Wtl,
    int n, int valid) {
  unsigned int bid = blockIdx.x;
  if (bid < SCAN_NB) {
    int i = bid * 256 + threadIdx.x;
    if (i < n) dc[i] = 1048576ull;   // self-loop weight 1.0, cnt 0
    if (bid == 0 && threadIdx.x < 64) {
      __shared__ int nz;
      if (threadIdx.x == 0) nz = 0;
      __syncthreads();
      if (ei[2 * threadIdx.x + 1] != 0) atomicAdd(&nz, 1);
      __syncthreads();
      if (threadIdx.x == 0) *flag = (nz == 0) ? 1 : 0;   // 1 => int64 layout
    }
  } else if (bid < SCAN_NB + CVT_XB) {
    int b = ((bid - SCAN_NB) * 256 + threadIdx.x) * 4;
    __half o[4];
    o[0] = __float2half_rn((b + 0 < valid) ? x[b + 0] : 0.f);
    o[1] = __float2half_rn((b + 1 < valid) ? x[b + 1] : 0.f);
    o[2] = __float2half_rn((b + 2 < valid) ? x[b + 2] : 0.f);
    o[3] = __float2half_rn((b + 3 < valid) ? x[b + 3] : 0.f);
    *(uint2*)(Hf + b) = *(const uint2*)o;
  } else {
    int i = (bid - SCAN_NB - CVT_XB) * 256 + threadIdx.x;   // 7*16384
    int l = i >> 14, r = i & 16383;
    int k = r >> 7, nn = r & 127;
    const float* src = (l == 0) ? W1 : (Wm + (size_t)(l - 1) * 16384);
    float v = src[k * 128 + nn];
    unsigned short h = f2b(v);
    int o = l * 16384 + nn * 128 + k;
    Wth[o] = h;
    Wtl[o] = f2b(v - b2f(h));
  }
}

// histogram; atomic's return value gives each edge its per-node ordinal (free)
__global__ __launch_bounds__(256) void prep_hist(const int* __restrict__ ei,
    const int* __restrict__ flag, const float* __restrict__ ew,
    unsigned long long* dc, unsigned short* __restrict__ ord, int e) {
  int i = blockIdx.x * 256 + threadIdx.x;
  if (i < e) {
    int f = *flag;
    int d = get_dst(ei, f, i);
    unsigned long long fx = (unsigned long long)(ew[i] * 1048576.0f + 0.5f);
    unsigned long long old = atomicAdd(&dc[d], (1ull << 32) | fx);
    ord[i] = (unsigned short)(old >> 32);
  }
}

// fused: dis compute + per-block cnt partial sum (cnt read from dc hi-word)
__global__ __launch_bounds__(256) void prep_dis_part(
    const unsigned long long* __restrict__ dc, float* dis,
    int* __restrict__ part, int n) {
  __shared__ int sb[256];
  int t = threadIdx.x, i = blockIdx.x * 256 + t;
  int c = 0;
  if (i < n) {
    unsigned long long v = dc[i];
    float d = (float)(unsigned int)(v & 0xffffffffull) * (1.0f / 1048576.0f);
    dis[i] = (d > 0.f) ? rsqrtf(d) : 0.f;
    c = (int)(v >> 32);
  }
  sb[t] = c;
  __syncthreads();
  for (int off = 128; off > 0; off >>= 1) {
    if (t < off) sb[t] += sb[t + off];
    __syncthreads();
  }
  if (t == 0) part[blockIdx.x] = sb[0];
}

// self-contained scan: each block scans the 196 partials in LDS then its own
// 256 counts (read from dc hi-word).
__global__ __launch_bounds__(256) void scan_apply(
    const unsigned long long* __restrict__ dc,
    const int* __restrict__ part, int* __restrict__ rowstart, int n, int e) {
  __shared__ int sp[256];
  __shared__ int sb[256];
  int t = threadIdx.x, i = blockIdx.x * 256 + t;
  int pv = (t < SCAN_NB) ? part[t] : 0;
  sp[t] = pv;
  int v = (i < n) ? (int)(dc[i] >> 32) : 0;
  sb[t] = v;
  __syncthreads();
  for (int off = 1; off < 256; off <<= 1) {
    int xa = (t >= off) ? sp[t - off] : 0;
    int xb = (t >= off) ? sb[t - off] : 0;
    __syncthreads();
    sp[t] += xa;
    sb[t] += xb;
    __syncthreads();
  }
  int partoff = (blockIdx.x > 0) ? sp[blockIdx.x - 1] : 0;  // exclusive of own block
  if (i < n) rowstart[i] = partoff + sb[t] - v;
  if (blockIdx.x == 0 && t == 0) rowstart[n] = e;
}

// packed 4B edge record: low16 = src node (N<65536), high16 = fp16 norm bits
__global__ __launch_bounds__(256) void prep_scatter(const int* __restrict__ ei,
    const int* __restrict__ flag, const float* __restrict__ ew,
    const float* __restrict__ dis, const int* __restrict__ rowstart,
    const unsigned short* __restrict__ ord, unsigned int* __restrict__ epack, int e) {
  int i = blockIdx.x * 256 + threadIdx.x;
  if (i >= e) return;
  int f = *flag;
  int d = get_dst(ei, f, i);
  int s = get_src(ei, f, i);
  int pos = rowstart[d] + (int)ord[i];
  float nm = dis[s] * ew[i] * dis[d];
  epack[pos] = (unsigned int)s | ((unsigned int)f2h_bits(nm) << 16);
}

// ---------------- MFMA split-bf16 GEMM: XW[MP,128] (fp16) = H @ W ----------------
// H stored as single fp16; exact bf16 hi/lo split reconstructed in-register.
__global__ __launch_bounds__(256) void gemm_mfma(
    const __half* __restrict__ Hf,
    const unsigned short* __restrict__ Bh, const unsigned short* __restrict__ Bl,
    __half* __restrict__ XW) {
  __shared__ float C[64][133];
  int t = threadIdx.x;
  int lane = t & 63, wv = t >> 6;
  int m16 = lane & 15, quad = lane >> 4;
  int rowbase = blockIdx.x * 128;
  int arow0 = rowbase + wv * 32 + m16;
  f32x4 acc0[8], acc1[8];
#pragma unroll
  for (int i = 0; i < 8; ++i) {
    acc0[i] = (f32x4){0.f, 0.f, 0.f, 0.f};
    acc1[i] = (f32x4){0.f, 0.f, 0.f, 0.f};
  }
  const __half* pf0 = Hf + (size_t)arow0 * 128 + quad * 8;
#pragma unroll
  for (int kc = 0; kc < 4; ++kc) {
    __half hb0[8], hb1[8];
    *(uint4*)hb0 = *(const uint4*)(pf0 + kc * 32);
    *(uint4*)hb1 = *(const uint4*)(pf0 + 16 * 128 + kc * 32);
    bf16x8 ah0, al0, ah1, al1;
    split8(hb0, ah0, al0);
    split8(hb1, ah1, al1);
    int k0 = kc * 32 + quad * 8;
#pragma unroll
    for (int tt = 0; tt < 8; ++tt) {
      int nn = tt * 16 + m16;
      bf16x8 bh = *(const bf16x8*)(Bh + nn * 128 + k0);
      bf16x8 bl = *(const bf16x8*)(Bl + nn * 128 + k0);
      acc0[tt] = __builtin_amdgcn_mfma_f32_16x16x32_bf16(ah0, bh, acc0[tt], 0, 0, 0);
      acc0[tt] = __builtin_amdgcn_mfma_f32_16x16x32_bf16(ah0, bl, acc0[tt], 0, 0, 0);
      acc0[tt] = __builtin_amdgcn_mfma_f32_16x16x32_bf16(al0, bh, acc0[tt], 0, 0, 0);
      acc1[tt] = __builtin_amdgcn_mfma_f32_16x16x32_bf16(ah1, bh, acc1[tt], 0, 0, 0);
      acc1[tt] = __builtin_amdgcn_mfma_f32_16x16x32_bf16(ah1, bl, acc1[tt], 0, 0, 0);
      acc1[tt] = __builtin_amdgcn_mfma_f32_16x16x32_bf16(al1, bh, acc1[tt], 0, 0, 0);
    }
  }
  int rr = t >> 2;               // 0..63
  int cb = (t & 3) * 32;         // col base
  int grow = rowbase + ((rr >> 4) << 5) + (rr & 15);
#pragma unroll
  for (int ph = 0; ph < 2; ++ph) {
    if (ph) __syncthreads();
#pragma unroll
    for (int tt = 0; tt < 8; ++tt)
#pragma unroll
      for (int r = 0; r < 4; ++r)
        C[wv * 16 + quad * 4 + r][tt * 16 + m16] = ph ? acc1[tt][r] : acc0[tt][r];
    __syncthreads();
    const float* crow = &C[rr][cb];
    __half2 o[16];
#pragma unroll
    for (int i = 0; i < 16; ++i) {
      __half2 h;
      h.x = __float2half_rn(crow[2 * i]);
      h.y = __float2half_rn(crow[2 * i + 1]);
      o[i] = h;
    }
    uint4* dst = (uint4*)(XW + (size_t)(grow + ph * 16) * 128 + cb);
    dst[0] = ((const uint4*)o)[0];
    dst[1] = ((const uint4*)o)[1];
    dst[2] = ((const uint4*)o)[2];
    dst[3] = ((const uint4*)o)[3];
  }
}

// ---------------- CSR aggregation + bias + relu -> fp16 H ----------------
// wave per node; 16 lanes cooperate per edge row (uint4 = 16B/lane), 4 edges
// in flight per lane-group. (r9/r12 lessons: no VGPR cap, 4-deep is optimal.)
__global__ __launch_bounds__(256) void agg_csr(const __half* __restrict__ XW,
    const int* __restrict__ rowstart, const unsigned int* __restrict__ epack,
    const float* __restrict__ dis, const float* __restrict__ bias,
    __half* __restrict__ Hf, int n) {
  int w = (blockIdx.x * 256 + threadIdx.x) >> 6;
  int l = threadIdx.x & 63;
  if (w >= n) return;
  int g = l >> 4;         // edge group 0..3
  int j = l & 15;         // column slice (8 cols each)
  float A[8];
#pragma unroll
  for (int k = 0; k < 8; ++k) A[k] = 0.f;
  int p = rowstart[w], p1 = rowstart[w + 1];
  for (; p < p1; p += 16) {
    int idx[4]; float wt[4];
#pragma unroll
    for (int u = 0; u < 4; ++u) {
      int pe = p + u * 4 + g;
      unsigned int rec = epack[pe];        // epack padded +16: safe overread
      bool inb = pe < p1;
      idx[u] = inb ? (int)(rec & 0xffffu) : w;
      wt[u] = inb ? h2f_bits((unsigned short)(rec >> 16)) : 0.f;
    }
    uint4 r[4];
#pragma unroll
    for (int u = 0; u < 4; ++u)
      r[u] = *(const uint4*)(XW + (size_t)idx[u] * 128 + j * 8);
#pragma unroll
    for (int u = 0; u < 4; ++u) {
      const __half2* h2 = (const __half2*)&r[u];
#pragma unroll
      for (int q = 0; q < 4; ++q) {
        A[2 * q + 0] = fmaf(wt[u], __low2float(h2[q]), A[2 * q + 0]);
        A[2 * q + 1] = fmaf(wt[u], __high2float(h2[q]), A[2 * q + 1]);
      }
    }
  }
  // reduce the 4 edge-groups (lanes l, l^16, l^32, l^48 hold same columns)
#pragma unroll
  for (int k = 0; k < 8; ++k) {
    A[k] += __shfl_xor(A[k], 16, 64);
    A[k] += __shfl_xor(A[k], 32, 64);
  }
  if (g == 0) {
    float dd = dis[w];
    float d2 = dd * dd;
    uint4 sr = *(const uint4*)(XW + (size_t)w * 128 + j * 8);
    const __half2* sh2 = (const __half2*)&sr;
    float4 b0 = *(const float4*)(bias + j * 8);
    float4 b1 = *(const float4*)(bias + j * 8 + 4);
    float bb[8] = {b0.x, b0.y, b0.z, b0.w, b1.x, b1.y, b1.z, b1.w};
    __half oh[8];
#pragma unroll
    for (int k = 0; k < 8; ++k) {
      float sv = (k & 1) ? __high2float(sh2[k >> 1]) : __low2float(sh2[k >> 1]);
      float v = fmaxf(A[k] + d2 * sv + bb[k], 0.f);
      oh[k] = __float2half_rn(v);
    }
    *(uint4*)(Hf + (size_t)w * 128 + j * 8) = *(const uint4*)oh;
  }
}

// ---------------- final layer ----------------
__global__ __launch_bounds__(256) void gemm_w8(const __half* __restrict__ Hf,
    const float* __restrict__ W8, float* __restrict__ XW2, int n) {
  __shared__ float w[256];
  int t = threadIdx.x;
  w[t] = W8[t];
  __syncthreads();
  int r = blockIdx.x * 256 + t;
  if (r >= n) return;
  const __half* hp = Hf + (size_t)r * 128;
  float a0 = 0.f, a1 = 0.f;
#pragma unroll
  for (int k = 0; k < 128; k += 4) {
    __half hb[4];
    *(uint2*)hb = *(const uint2*)(hp + k);
    float h0 = __half2float(hb[0]);
    float h1 = __half2float(hb[1]);
    float h2 = __half2float(hb[2]);
    float h3 = __half2float(hb[3]);
    a0 += h0 * w[2 * k + 0] + h1 * w[2 * k + 2] + h2 * w[2 * k + 4] + h3 * w[2 * k + 6];
    a1 += h0 * w[2 * k + 1] + h1 * w[2 * k + 3] + h2 * w[2 * k + 5] + h3 * w[2 * k + 7];
  }
  XW2[r * 2 + 0] = a0;
  XW2[r * 2 + 1] = a1;
}

__global__ __launch_bounds__(256) void agg_final(const float* __restrict__ XW2,
    const int* __restrict__ rowstart, const unsigned int* __restrict__ epack,
    const float* __restrict__ dis, const float* __restrict__ b8,
    float* __restrict__ out, int n) {
  int i = blockIdx.x * 256 + threadIdx.x;
  if (i >= n) return;
  float d = dis[i], d2 = d * d;
  float a0 = d2 * XW2[i * 2 + 0];
  float a1 = d2 * XW2[i * 2 + 1];
  int p1 = rowstart[i + 1];
  for (int p = rowstart[i]; p < p1; ++p) {
    unsigned int rec = epack[p];
    int s = (int)(rec & 0xffffu);
    float wt = h2f_bits((unsigned short)(rec >> 16));
    a0 = fmaf(wt, XW2[s * 2 + 0], a0);
    a1 = fmaf(wt, XW2[s * 2 + 1], a1);
  }
  out[i * 2 + 0] = a0 + b8[0];
  out[i * 2 + 1] = a1 + b8[1];
}

// ---------------- launcher ----------------
static inline char* alignp(char* p) {
  return (char*)(((uintptr_t)p + 255) & ~(uintptr_t)255);
}

extern "C" void kernel_launch(void* const* d_in, const int* in_sizes, int n_in,
                              void* d_out, int out_size, void* d_ws, size_t ws_size,
                              hipStream_t stream) {
  (void)in_sizes; (void)n_in; (void)out_size; (void)ws_size;
  const int n = NN, e = NE;
  const float* x  = (const float*)d_in[0];
  const int*   ei = (const int*)d_in[1];
  const float* ea = (const float*)d_in[2];
  const float* W1 = (const float*)d_in[3];
  const float* b1 = (const float*)d_in[4];
  const float* Wm = (const float*)d_in[5];
  const float* bm = (const float*)d_in[6];
  const float* W8 = (const float*)d_in[7];
  const float* b8 = (const float*)d_in[8];
  float* out = (float*)d_out;

  char* w = (char*)d_ws;
  int*   flag   = (int*)w;            w = alignp(w + 4);
  int*   part   = (int*)w;            w = alignp(w + SCAN_NB * 4);
  unsigned long long* dc = (unsigned long long*)w; w = alignp(w + (size_t)n * 8);
  float* dis    = (float*)w;          w = alignp(w + (size_t)n * 4);
  int*   rowst  = (int*)w;            w = alignp(w + (size_t)(n + 1) * 4);
  unsigned short* ord = (unsigned short*)w;  w = alignp(w + (size_t)e * 2);
  unsigned int* epack = (unsigned int*)w;    w = alignp(w + (size_t)(e + 32) * 4);
  __half* Hf = (__half*)w;            w = alignp(w + (size_t)MP * 128 * 2);
  unsigned short* Wth = (unsigned short*)w;  w = alignp(w + (size_t)7 * 16384 * 2);
  unsigned short* Wtl = (unsigned short*)w;  w = alignp(w + (size_t)7 * 16384 * 2);
  __half* XW  = (__half*)w;           w = alignp(w + (size_t)MP * 128 * 2);
  float* XW2  = (float*)w;            w = alignp(w + (size_t)MP * 2 * 4);

  const int GN = (n + 255) / 256;

  prep_fused<<<SCAN_NB + CVT_XB + CVT_WB, 256, 0, stream>>>(
      ei, flag, dc, x, Hf, W1, Wm, Wth, Wtl, n, n * 128);
  prep_hist<<<GE_NB, 256, 0, stream>>>(ei, flag, ea, dc, ord, e);
  prep_dis_part<<<SCAN_NB, 256, 0, stream>>>(dc, dis, part, n);
  scan_apply<<<SCAN_NB, 256, 0, stream>>>(dc, part, rowst, n, e);
  prep_scatter<<<GE_NB, 256, 0, stream>>>(ei, flag, ea, dis, rowst, ord, epack, e);

  for (int l = 0; l < 7; ++l) {
    const unsigned short* Bh = Wth + (size_t)l * 16384;
    const unsigned short* Bl = Wtl + (size_t)l * 16384;
    const float* bl = (l == 0) ? b1 : bm + (size_t)(l - 1) * 128;
    gemm_mfma<<<MP / 128, 256, 0, stream>>>(Hf, Bh, Bl, XW);
    agg_csr<<<(n * 64 + 255) / 256, 256, 0, stream>>>(XW, rowst, epack, dis, bl, Hf, n);
  }
  gemm_w8<<<GN, 256, 0, stream>>>(Hf, W8, XW2, n);
  agg_final<<<GN, 256, 0, stream>>>(XW2, rowst, epack, dis, b8, out, n);
}

// Round 15
// 544.098 us; speedup vs baseline: 1.0216x; 1.0216x over previous
//
#include <hip/hip_runtime.h>
#include <hip/hip_bf16.h>
#include <hip/hip_fp16.h>

#define NN 50000
#define NE 800000
#define MP 50048            // NN padded to multiple of 128
#define SCAN_NB 196         // ceil(NN/256)
#define GE_NB 3125          // ceil(NE/256)
#define CVT_WB 448          // 7*16384/256 blocks for w conversion

typedef __bf16 bf16x8 __attribute__((ext_vector_type(8)));
typedef unsigned short u16x8 __attribute__((ext_vector_type(8)));
typedef float f32x4 __attribute__((ext_vector_type(4)));

static __device__ __forceinline__ float b2f(unsigned short u) {
  union { unsigned int i; float f; } v; v.i = ((unsigned int)u) << 16; return v.f;
}
static __device__ __forceinline__ unsigned short f2b(float f) {
  __hip_bfloat16 h = __float2bfloat16(f);
  union { __hip_bfloat16 h; unsigned short u; } v; v.h = h; return v.u;
}
static __device__ __forceinline__ float h2f_bits(unsigned short u) {
  __half h; union { __half h; unsigned short u; } v; v.u = u; h = v.h;
  return __half2float(h);
}
static __device__ __forceinline__ unsigned short f2h_bits(float f) {
  union { __half h; unsigned short u; } v; v.h = __float2half_rn(f); return v.u;
}

static __device__ __forceinline__ int get_src(const int* ei, int f, int i) {
  return f ? ei[2 * i] : ei[i];
}
static __device__ __forceinline__ int get_dst(const int* ei, int f, int i) {
  return f ? ei[2 * (NE + i)] : ei[NE + i];
}

// exact bf16 hi/lo split of 8 fp16 values
static __device__ __forceinline__ void split8(const __half* h8, bf16x8& ah, bf16x8& al) {
  u16x8 hu, lu;
#pragma unroll
  for (int i = 0; i < 8; ++i) {
    float f = __half2float(h8[i]);
    unsigned uf = __float_as_uint(f);
    unsigned hb = uf & 0xffff0000u;
    hu[i] = (unsigned short)(hb >> 16);
    float lo = f - __uint_as_float(hb);
    lu[i] = (unsigned short)(__float_as_uint(lo) >> 16);
  }
  ah = *(bf16x8*)&hu;
  al = *(bf16x8*)&lu;
}

// rn bf16 hi/lo split of 8 fp32 values (hi=rn(v), lo=rn(v-hi); drops ~2^-16)
static __device__ __forceinline__ void split8f(const float* f8, bf16x8& ah, bf16x8& al) {
  u16x8 hu, lu;
#pragma unroll
  for (int i = 0; i < 8; ++i) {
    unsigned short h = f2b(f8[i]);
    hu[i] = h;
    lu[i] = f2b(f8[i] - b2f(h));
  }
  ah = *(bf16x8*)&hu;
  al = *(bf16x8*)&lu;
}

// ---------------- fused: flag detect + dc init + cvt_w ----------------
__global__ __launch_bounds__(256) void prep_fused(const int* __restrict__ ei,
    int* flag, unsigned long long* dc,
    const float* __restrict__ W1, const float* __restrict__ Wm,
    unsigned short* __restrict__ Wth, unsigned short* __restrict__ Wtl, int n) {
  unsigned int bid = blockIdx.x;
  if (bid < SCAN_NB) {
    int i = bid * 256 + threadIdx.x;
    if (i < n) dc[i] = 1048576ull;   // self-loop weight 1.0, cnt 0
    if (bid == 0 && threadIdx.x < 64) {
      __shared__ int nz;
      if (threadIdx.x == 0) nz = 0;
      __syncthreads();
      if (ei[2 * threadIdx.x + 1] != 0) atomicAdd(&nz, 1);
      __syncthreads();
      if (threadIdx.x == 0) *flag = (nz == 0) ? 1 : 0;   // 1 => int64 layout
    }
  } else {
    int i = (bid - SCAN_NB) * 256 + threadIdx.x;   // 7*16384
    int l = i >> 14, r = i & 16383;
    int k = r >> 7, nn = r & 127;
    const float* src = (l == 0) ? W1 : (Wm + (size_t)(l - 1) * 16384);
    float v = src[k * 128 + nn];
    unsigned short h = f2b(v);
    int o = l * 16384 + nn * 128 + k;
    Wth[o] = h;
    Wtl[o] = f2b(v - b2f(h));
  }
}

// histogram; atomic's return value gives each edge its per-node ordinal (free)
__global__ __launch_bounds__(256) void prep_hist(const int* __restrict__ ei,
    const int* __restrict__ flag, const float* __restrict__ ew,
    unsigned long long* dc, unsigned short* __restrict__ ord, int e) {
  int i = blockIdx.x * 256 + threadIdx.x;
  if (i < e) {
    int f = *flag;
    int d = get_dst(ei, f, i);
    unsigned long long fx = (unsigned long long)(ew[i] * 1048576.0f + 0.5f);
    unsigned long long old = atomicAdd(&dc[d], (1ull << 32) | fx);
    ord[i] = (unsigned short)(old >> 32);
  }
}

// fused: dis compute + per-block cnt partial sum (cnt read from dc hi-word)
__global__ __launch_bounds__(256) void prep_dis_part(
    const unsigned long long* __restrict__ dc, float* dis,
    int* __restrict__ part, int n) {
  __shared__ int sb[256];
  int t = threadIdx.x, i = blockIdx.x * 256 + t;
  int c = 0;
  if (i < n) {
    unsigned long long v = dc[i];
    float d = (float)(unsigned int)(v & 0xffffffffull) * (1.0f / 1048576.0f);
    dis[i] = (d > 0.f) ? rsqrtf(d) : 0.f;
    c = (int)(v >> 32);
  }
  sb[t] = c;
  __syncthreads();
  for (int off = 128; off > 0; off >>= 1) {
    if (t < off) sb[t] += sb[t + off];
    __syncthreads();
  }
  if (t == 0) part[blockIdx.x] = sb[0];
}

// self-contained scan: each block scans the 196 partials in LDS then its own
// 256 counts (read from dc hi-word).
__global__ __launch_bounds__(256) void scan_apply(
    const unsigned long long* __restrict__ dc,
    const int* __restrict__ part, int* __restrict__ rowstart, int n, int e) {
  __shared__ int sp[256];
  __shared__ int sb[256];
  int t = threadIdx.x, i = blockIdx.x * 256 + t;
  int pv = (t < SCAN_NB) ? part[t] : 0;
  sp[t] = pv;
  int v = (i < n) ? (int)(dc[i] >> 32) : 0;
  sb[t] = v;
  __syncthreads();
  for (int off = 1; off < 256; off <<= 1) {
    int xa = (t >= off) ? sp[t - off] : 0;
    int xb = (t >= off) ? sb[t - off] : 0;
    __syncthreads();
    sp[t] += xa;
    sb[t] += xb;
    __syncthreads();
  }
  int partoff = (blockIdx.x > 0) ? sp[blockIdx.x - 1] : 0;  // exclusive of own block
  if (i < n) rowstart[i] = partoff + sb[t] - v;
  if (blockIdx.x == 0 && t == 0) rowstart[n] = e;
}

// packed 4B edge record: low16 = src node (N<65536), high16 = fp16 norm bits
__global__ __launch_bounds__(256) void prep_scatter(const int* __restrict__ ei,
    const int* __restrict__ flag, const float* __restrict__ ew,
    const float* __restrict__ dis, const int* __restrict__ rowstart,
    const unsigned short* __restrict__ ord, unsigned int* __restrict__ epack, int e) {
  int i = blockIdx.x * 256 + threadIdx.x;
  if (i >= e) return;
  int f = *flag;
  int d = get_dst(ei, f, i);
  int s = get_src(ei, f, i);
  int pos = rowstart[d] + (int)ord[i];
  float nm = dis[s] * ew[i] * dis[d];
  epack[pos] = (unsigned int)s | ((unsigned int)f2h_bits(nm) << 16);
}

// ---------------- shared GEMM epilogue: C (LDS transpose) -> fp16 XW ----------------
static __device__ __forceinline__ void gemm_epilogue(float (*C)[133],
    f32x4* acc0, f32x4* acc1, int t, int wv, int quad, int m16,
    int rowbase, __half* __restrict__ XW) {
  int rr = t >> 2;               // 0..63
  int cb = (t & 3) * 32;         // col base
  int grow = rowbase + ((rr >> 4) << 5) + (rr & 15);
#pragma unroll
  for (int ph = 0; ph < 2; ++ph) {
    if (ph) __syncthreads();
#pragma unroll
    for (int tt = 0; tt < 8; ++tt)
#pragma unroll
      for (int r = 0; r < 4; ++r)
        C[wv * 16 + quad * 4 + r][tt * 16 + m16] = ph ? acc1[tt][r] : acc0[tt][r];
    __syncthreads();
    const float* crow = &C[rr][cb];
    __half2 o[16];
#pragma unroll
    for (int i = 0; i < 16; ++i) {
      __half2 h;
      h.x = __float2half_rn(crow[2 * i]);
      h.y = __float2half_rn(crow[2 * i + 1]);
      o[i] = h;
    }
    uint4* dst = (uint4*)(XW + (size_t)(grow + ph * 16) * 128 + cb);
    dst[0] = ((const uint4*)o)[0];
    dst[1] = ((const uint4*)o)[1];
    dst[2] = ((const uint4*)o)[2];
    dst[3] = ((const uint4*)o)[3];
  }
}

// ---------------- layer-0 GEMM: XW = x(fp32) @ W1, in-register split ----------------
__global__ __launch_bounds__(256) void gemm_x(const float* __restrict__ X,
    const unsigned short* __restrict__ Bh, const unsigned short* __restrict__ Bl,
    __half* __restrict__ XW) {
  __shared__ float C[64][133];
  int t = threadIdx.x;
  int lane = t & 63, wv = t >> 6;
  int m16 = lane & 15, quad = lane >> 4;
  int rowbase = blockIdx.x * 128;
  int arow0 = rowbase + wv * 32 + m16;
  int arow1 = arow0 + 16;
  f32x4 acc0[8], acc1[8];
#pragma unroll
  for (int i = 0; i < 8; ++i) {
    acc0[i] = (f32x4){0.f, 0.f, 0.f, 0.f};
    acc1[i] = (f32x4){0.f, 0.f, 0.f, 0.f};
  }
  const float* px0 = X + (size_t)arow0 * 128 + quad * 8;
  bool v0 = arow0 < NN, v1 = arow1 < NN;
#pragma unroll
  for (int kc = 0; kc < 4; ++kc) {
    float af0[8], af1[8];
    if (v0) {
      *(float4*)&af0[0] = *(const float4*)(px0 + kc * 32);
      *(float4*)&af0[4] = *(const float4*)(px0 + kc * 32 + 4);
    } else {
#pragma unroll
      for (int i = 0; i < 8; ++i) af0[i] = 0.f;
    }
    if (v1) {
      *(float4*)&af1[0] = *(const float4*)(px0 + 16 * 128 + kc * 32);
      *(float4*)&af1[4] = *(const float4*)(px0 + 16 * 128 + kc * 32 + 4);
    } else {
#pragma unroll
      for (int i = 0; i < 8; ++i) af1[i] = 0.f;
    }
    bf16x8 ah0, al0, ah1, al1;
    split8f(af0, ah0, al0);
    split8f(af1, ah1, al1);
    int k0 = kc * 32 + quad * 8;
#pragma unroll
    for (int tt = 0; tt < 8; ++tt) {
      int nn = tt * 16 + m16;
      bf16x8 bh = *(const bf16x8*)(Bh + nn * 128 + k0);
      bf16x8 bl = *(const bf16x8*)(Bl + nn * 128 + k0);
      acc0[tt] = __builtin_amdgcn_mfma_f32_16x16x32_bf16(ah0, bh, acc0[tt], 0, 0, 0);
      acc0[tt] = __builtin_amdgcn_mfma_f32_16x16x32_bf16(ah0, bl, acc0[tt], 0, 0, 0);
      acc0[tt] = __builtin_amdgcn_mfma_f32_16x16x32_bf16(al0, bh, acc0[tt], 0, 0, 0);
      acc1[tt] = __builtin_amdgcn_mfma_f32_16x16x32_bf16(ah1, bh, acc1[tt], 0, 0, 0);
      acc1[tt] = __builtin_amdgcn_mfma_f32_16x16x32_bf16(ah1, bl, acc1[tt], 0, 0, 0);
      acc1[tt] = __builtin_amdgcn_mfma_f32_16x16x32_bf16(al1, bh, acc1[tt], 0, 0, 0);
    }
  }
  gemm_epilogue(C, acc0, acc1, t, wv, quad, m16, rowbase, XW);
}

// ---------------- layers 1..6 GEMM: XW = Hf(fp16) @ W ----------------
__global__ __launch_bounds__(256) void gemm_mfma(
    const __half* __restrict__ Hf,
    const unsigned short* __restrict__ Bh, const unsigned short* __restrict__ Bl,
    __half* __restrict__ XW) {
  __shared__ float C[64][133];
  int t = threadIdx.x;
  int lane = t & 63, wv = t >> 6;
  int m16 = lane & 15, quad = lane >> 4;
  int rowbase = blockIdx.x * 128;
  int arow0 = rowbase + wv * 32 + m16;
  f32x4 acc0[8], acc1[8];
#pragma unroll
  for (int i = 0; i < 8; ++i) {
    acc0[i] = (f32x4){0.f, 0.f, 0.f, 0.f};
    acc1[i] = (f32x4){0.f, 0.f, 0.f, 0.f};
  }
  const __half* pf0 = Hf + (size_t)arow0 * 128 + quad * 8;
#pragma unroll
  for (int kc = 0; kc < 4; ++kc) {
    __half hb0[8], hb1[8];
    *(uint4*)hb0 = *(const uint4*)(pf0 + kc * 32);
    *(uint4*)hb1 = *(const uint4*)(pf0 + 16 * 128 + kc * 32);
    bf16x8 ah0, al0, ah1, al1;
    split8(hb0, ah0, al0);
    split8(hb1, ah1, al1);
    int k0 = kc * 32 + quad * 8;
#pragma unroll
    for (int tt = 0; tt < 8; ++tt) {
      int nn = tt * 16 + m16;
      bf16x8 bh = *(const bf16x8*)(Bh + nn * 128 + k0);
      bf16x8 bl = *(const bf16x8*)(Bl + nn * 128 + k0);
      acc0[tt] = __builtin_amdgcn_mfma_f32_16x16x32_bf16(ah0, bh, acc0[tt], 0, 0, 0);
      acc0[tt] = __builtin_amdgcn_mfma_f32_16x16x32_bf16(ah0, bl, acc0[tt], 0, 0, 0);
      acc0[tt] = __builtin_amdgcn_mfma_f32_16x16x32_bf16(al0, bh, acc0[tt], 0, 0, 0);
      acc1[tt] = __builtin_amdgcn_mfma_f32_16x16x32_bf16(ah1, bh, acc1[tt], 0, 0, 0);
      acc1[tt] = __builtin_amdgcn_mfma_f32_16x16x32_bf16(ah1, bl, acc1[tt], 0, 0, 0);
      acc1[tt] = __builtin_amdgcn_mfma_f32_16x16x32_bf16(al1, bh, acc1[tt], 0, 0, 0);
    }
  }
  gemm_epilogue(C, acc0, acc1, t, wv, quad, m16, rowbase, XW);
}

// ---------------- CSR aggregation + bias + relu -> fp16 H (layers 1..6) ----------------
__global__ __launch_bounds__(256) void agg_csr(const __half* __restrict__ XW,
    const int* __restrict__ rowstart, const unsigned int* __restrict__ epack,
    const float* __restrict__ dis, const float* __restrict__ bias,
    __half* __restrict__ Hf, int n) {
  int w = (blockIdx.x * 256 + threadIdx.x) >> 6;
  int l = threadIdx.x & 63;
  if (w >= n) return;
  int g = l >> 4;         // edge group 0..3
  int j = l & 15;         // column slice (8 cols each)
  float A[8];
#pragma unroll
  for (int k = 0; k < 8; ++k) A[k] = 0.f;
  int p = rowstart[w], p1 = rowstart[w + 1];
  for (; p < p1; p += 16) {
    int idx[4]; float wt[4];
#pragma unroll
    for (int u = 0; u < 4; ++u) {
      int pe = p + u * 4 + g;
      unsigned int rec = epack[pe];        // epack padded: safe overread
      bool inb = pe < p1;
      idx[u] = inb ? (int)(rec & 0xffffu) : w;
      wt[u] = inb ? h2f_bits((unsigned short)(rec >> 16)) : 0.f;
    }
    uint4 r[4];
#pragma unroll
    for (int u = 0; u < 4; ++u)
      r[u] = *(const uint4*)(XW + (size_t)idx[u] * 128 + j * 8);
#pragma unroll
    for (int u = 0; u < 4; ++u) {
      const __half2* h2 = (const __half2*)&r[u];
#pragma unroll
      for (int q = 0; q < 4; ++q) {
        A[2 * q + 0] = fmaf(wt[u], __low2float(h2[q]), A[2 * q + 0]);
        A[2 * q + 1] = fmaf(wt[u], __high2float(h2[q]), A[2 * q + 1]);
      }
    }
  }
#pragma unroll
  for (int k = 0; k < 8; ++k) {
    A[k] += __shfl_xor(A[k], 16, 64);
    A[k] += __shfl_xor(A[k], 32, 64);
  }
  if (g == 0) {
    float dd = dis[w];
    float d2 = dd * dd;
    uint4 sr = *(const uint4*)(XW + (size_t)w * 128 + j * 8);
    const __half2* sh2 = (const __half2*)&sr;
    float4 b0 = *(const float4*)(bias + j * 8);
    float4 b1 = *(const float4*)(bias + j * 8 + 4);
    float bb[8] = {b0.x, b0.y, b0.z, b0.w, b1.x, b1.y, b1.z, b1.w};
    __half oh[8];
#pragma unroll
    for (int k = 0; k < 8; ++k) {
      float sv = (k & 1) ? __high2float(sh2[k >> 1]) : __low2float(sh2[k >> 1]);
      float v = fmaxf(A[k] + d2 * sv + bb[k], 0.f);
      oh[k] = __float2half_rn(v);
    }
    *(uint4*)(Hf + (size_t)w * 128 + j * 8) = *(const uint4*)oh;
  }
}

// ---------------- layer-7 agg fused with W8 projection -> XW2 ----------------
// n = 50000 is divisible by 4, so every block is full (LDS sync is safe).
__global__ __launch_bounds__(256) void agg_csr7(const __half* __restrict__ XW,
    const int* __restrict__ rowstart, const unsigned int* __restrict__ epack,
    const float* __restrict__ dis, const float* __restrict__ bias,
    const float* __restrict__ W8, float* __restrict__ XW2, int n) {
  __shared__ float ws[256];
  ws[threadIdx.x] = W8[threadIdx.x];
  __syncthreads();
  int w = (blockIdx.x * 256 + threadIdx.x) >> 6;
  int l = threadIdx.x & 63;
  if (w >= n) return;
  int g = l >> 4;
  int j = l & 15;
  float A[8];
#pragma unroll
  for (int k = 0; k < 8; ++k) A[k] = 0.f;
  int p = rowstart[w], p1 = rowstart[w + 1];
  for (; p < p1; p += 16) {
    int idx[4]; float wt[4];
#pragma unroll
    for (int u = 0; u < 4; ++u) {
      int pe = p + u * 4 + g;
      unsigned int rec = epack[pe];
      bool inb = pe < p1;
      idx[u] = inb ? (int)(rec & 0xffffu) : w;
      wt[u] = inb ? h2f_bits((unsigned short)(rec >> 16)) : 0.f;
    }
    uint4 r[4];
#pragma unroll
    for (int u = 0; u < 4; ++u)
      r[u] = *(const uint4*)(XW + (size_t)idx[u] * 128 + j * 8);
#pragma unroll
    for (int u = 0; u < 4; ++u) {
      const __half2* h2 = (const __half2*)&r[u];
#pragma unroll
      for (int q = 0; q < 4; ++q) {
        A[2 * q + 0] = fmaf(wt[u], __low2float(h2[q]), A[2 * q + 0]);
        A[2 * q + 1] = fmaf(wt[u], __high2float(h2[q]), A[2 * q + 1]);
      }
    }
  }
#pragma unroll
  for (int k = 0; k < 8; ++k) {
    A[k] += __shfl_xor(A[k], 16, 64);  // after these two, ALL lanes hold
    A[k] += __shfl_xor(A[k], 32, 64);  // the full column sums for slice j
  }
  // finish h = relu(agg + self + bias), then project to 2 outputs via W8
  float dd = dis[w];
  float d2 = dd * dd;
  uint4 sr = *(const uint4*)(XW + (size_t)w * 128 + j * 8);
  const __half2* sh2 = (const __half2*)&sr;
  float4 b0 = *(const float4*)(bias + j * 8);
  float4 b1 = *(const float4*)(bias + j * 8 + 4);
  float bb[8] = {b0.x, b0.y, b0.z, b0.w, b1.x, b1.y, b1.z, b1.w};
  float a0 = 0.f, a1 = 0.f;
#pragma unroll
  for (int k = 0; k < 8; ++k) {
    float sv = (k & 1) ? __high2float(sh2[k >> 1]) : __low2float(sh2[k >> 1]);
    float v = fmaxf(A[k] + d2 * sv + bb[k], 0.f);
    int col = j * 8 + k;
    a0 = fmaf(v, ws[col * 2 + 0], a0);
    a1 = fmaf(v, ws[col * 2 + 1], a1);
  }
  // reduce over the 16 column slices (within each 16-lane group)
#pragma unroll
  for (int m = 1; m <= 8; m <<= 1) {
    a0 += __shfl_xor(a0, m, 64);
    a1 += __shfl_xor(a1, m, 64);
  }
  if (l == 0) {
    XW2[w * 2 + 0] = a0;
    XW2[w * 2 + 1] = a1;
  }
}

// ---------------- final aggregation -> fp32 out ----------------
__global__ __launch_bounds__(256) void agg_final(const float* __restrict__ XW2,
    const int* __restrict__ rowstart, const unsigned int* __restrict__ epack,
    const float* __restrict__ dis, const float* __restrict__ b8,
    float* __restrict__ out, int n) {
  int i = blockIdx.x * 256 + threadIdx.x;
  if (i >= n) return;
  float d = dis[i], d2 = d * d;
  float a0 = d2 * XW2[i * 2 + 0];
  float a1 = d2 * XW2[i * 2 + 1];
  int p1 = rowstart[i + 1];
  for (int p = rowstart[i]; p < p1; ++p) {
    unsigned int rec = epack[p];
    int s = (int)(rec & 0xffffu);
    float wt = h2f_bits((unsigned short)(rec >> 16));
    a0 = fmaf(wt, XW2[s * 2 + 0], a0);
    a1 = fmaf(wt, XW2[s * 2 + 1], a1);
  }
  out[i * 2 + 0] = a0 + b8[0];
  out[i * 2 + 1] = a1 + b8[1];
}

// ---------------- launcher ----------------
static inline char* alignp(char* p) {
  return (char*)(((uintptr_t)p + 255) & ~(uintptr_t)255);
}

extern "C" void kernel_launch(void* const* d_in, const int* in_sizes, int n_in,
                              void* d_out, int out_size, void* d_ws, size_t ws_size,
                              hipStream_t stream) {
  (void)in_sizes; (void)n_in; (void)out_size; (void)ws_size;
  const int n = NN, e = NE;
  const float* x  = (const float*)d_in[0];
  const int*   ei = (const int*)d_in[1];
  const float* ea = (const float*)d_in[2];
  const float* W1 = (const float*)d_in[3];
  const float* b1 = (const float*)d_in[4];
  const float* Wm = (const float*)d_in[5];
  const float* bm = (const float*)d_in[6];
  const float* W8 = (const float*)d_in[7];
  const float* b8 = (const float*)d_in[8];
  float* out = (float*)d_out;

  char* w = (char*)d_ws;
  int*   flag   = (int*)w;            w = alignp(w + 4);
  int*   part   = (int*)w;            w = alignp(w + SCAN_NB * 4);
  unsigned long long* dc = (unsigned long long*)w; w = alignp(w + (size_t)n * 8);
  float* dis    = (float*)w;          w = alignp(w + (size_t)n * 4);
  int*   rowst  = (int*)w;            w = alignp(w + (size_t)(n + 1) * 4);
  unsigned short* ord = (unsigned short*)w;  w = alignp(w + (size_t)e * 2);
  unsigned int* epack = (unsigned int*)w;    w = alignp(w + (size_t)(e + 32) * 4);
  __half* Hf = (__half*)w;            w = alignp(w + (size_t)MP * 128 * 2);
  unsigned short* Wth = (unsigned short*)w;  w = alignp(w + (size_t)7 * 16384 * 2);
  unsigned short* Wtl = (unsigned short*)w;  w = alignp(w + (size_t)7 * 16384 * 2);
  __half* XW  = (__half*)w;           w = alignp(w + (size_t)MP * 128 * 2);
  float* XW2  = (float*)w;            w = alignp(w + (size_t)MP * 2 * 4);

  const int GN = (n + 255) / 256;
  const int AGG_NB = (n * 64 + 255) / 256;   // 12500 exactly (n % 4 == 0)

  prep_fused<<<SCAN_NB + CVT_WB, 256, 0, stream>>>(ei, flag, dc, W1, Wm, Wth, Wtl, n);
  prep_hist<<<GE_NB, 256, 0, stream>>>(ei, flag, ea, dc, ord, e);
  prep_dis_part<<<SCAN_NB, 256, 0, stream>>>(dc, dis, part, n);
  scan_apply<<<SCAN_NB, 256, 0, stream>>>(dc, part, rowst, n, e);
  prep_scatter<<<GE_NB, 256, 0, stream>>>(ei, flag, ea, dis, rowst, ord, epack, e);

  // layer 0: GEMM reads fp32 x directly
  gemm_x<<<MP / 128, 256, 0, stream>>>(x, Wth, Wtl, XW);
  agg_csr<<<AGG_NB, 256, 0, stream>>>(XW, rowst, epack, dis, b1, Hf, n);

  // layers 1..5: standard gemm+agg
  for (int l = 1; l < 6; ++l) {
    const unsigned short* Bh = Wth + (size_t)l * 16384;
    const unsigned short* Bl = Wtl + (size_t)l * 16384;
    const float* bl = bm + (size_t)(l - 1) * 128;
    gemm_mfma<<<MP / 128, 256, 0, stream>>>(Hf, Bh, Bl, XW);
    agg_csr<<<AGG_NB, 256, 0, stream>>>(XW, rowst, epack, dis, bl, Hf, n);
  }
  // layer 6 (conv 7): agg fused with W8 projection
  gemm_mfma<<<MP / 128, 256, 0, stream>>>(Hf, Wth + (size_t)6 * 16384,
                                          Wtl + (size_t)6 * 16384, XW);
  agg_csr7<<<AGG_NB, 256, 0, stream>>>(XW, rowst, epack, dis,
                                       bm + (size_t)5 * 128, W8, XW2, n);
  agg_final<<<GN, 256, 0, stream>>>(XW2, rowst, epack, dis, b8, out, n);
}